// Round 6
// baseline (77.311 us; speedup 1.0000x reference)
//
#include <hip/hip_runtime.h>
#include <hip/hip_bf16.h>

#define L_Q 4096
#define NB 2
#define DMODEL 512
#define NHEAD 8
#define DHEAD 64
#define SPAN_ 32

using short8 = __attribute__((ext_vector_type(8))) short;
using f32x4  = __attribute__((ext_vector_type(4))) float;

typedef __attribute__((address_space(1))) const void GV;
typedef __attribute__((address_space(3))) void LV;

__device__ __forceinline__ void gl2lds16(const void* g, void* l) {
    __builtin_amdgcn_global_load_lds((GV*)g, (LV*)l, 16, 0, 0);
}

__device__ __forceinline__ float bf2f(short u) {
    return __uint_as_float(((unsigned)(unsigned short)u) << 16);
}
__device__ __forceinline__ short f2bf(float f) {
    __hip_bfloat16 h = __float2bfloat16(f);
    return *reinterpret_cast<short*>(&h);
}
__device__ __forceinline__ unsigned packbf(float lo, float hi) {
    return (unsigned)(unsigned short)f2bf(lo) | ((unsigned)(unsigned short)f2bf(hi) << 16);
}

// ---------------- weight transpose+cast x4: Wt[n][k] = bf16(W[k][n]) ----------------
__global__ __launch_bounds__(256) void castT4_bf16(
    const float* __restrict__ Wq, const float* __restrict__ Wk,
    const float* __restrict__ Wv, const float* __restrict__ Wo,
    short* __restrict__ Wtq, short* __restrict__ Wtk,
    short* __restrict__ Wtv, short* __restrict__ Wto)
{
    const int z = blockIdx.z;
    const float* W = (z == 0) ? Wq : ((z == 1) ? Wk : ((z == 2) ? Wv : Wo));
    short* Wt = (z == 0) ? Wtq : ((z == 1) ? Wtk : ((z == 2) ? Wtv : Wto));
    __shared__ float t[32][33];
    const int tx = threadIdx.x, ty = threadIdx.y;
    const int bx = blockIdx.x, by = blockIdx.y;
#pragma unroll
    for (int i = 0; i < 4; ++i)
        t[ty + i * 8][tx] = W[(size_t)(by * 32 + ty + i * 8) * DMODEL + bx * 32 + tx];
    __syncthreads();
#pragma unroll
    for (int i = 0; i < 4; ++i)
        Wt[(size_t)(bx * 32 + ty + i * 8) * DMODEL + by * 32 + tx] = f2bf(t[tx][ty + i * 8]);
}

// ---------------- 128x128 MFMA GEMM core (BK=64, 4 waves, wave = 64x64) ----------------
// OUTMODE 0: f32 row-major. 1: bf16 row-major. 2: bf16 Vt[bh][d][g].
// ACAST: A is f32, cast to bf16 during reg-staging (same swizzled LDS layout).
template<int OUTMODE, bool ACAST>
__device__ __forceinline__ void gemm128_body(
    const void* __restrict__ Avoid, const short* __restrict__ Bt, void* __restrict__ Cout,
    short* As, short* Bs)
{
    const int tid = threadIdx.x;
    const int m0 = blockIdx.y * 128;
    const int n0 = blockIdx.x * 128;
    const int w = tid >> 6, lane = tid & 63;
    const int wr = w & 1, wc = w >> 1;
    const int l15 = lane & 15, l4 = lane >> 4;

    f32x4 acc[4][4];
#pragma unroll
    for (int fm = 0; fm < 4; ++fm)
#pragma unroll
        for (int fn = 0; fn < 4; ++fn) acc[fm][fn] = (f32x4){0.f, 0.f, 0.f, 0.f};

    for (int k0 = 0; k0 < DMODEL; k0 += 64) {
        __syncthreads();
        if (ACAST) {
            const float* Af = (const float*)Avoid;
#pragma unroll
            for (int it = 0; it < 4; ++it) {       // A tile: 128 rows x 8 chunks, f32->bf16
                int c = it * 256 + tid;
                int row = c >> 3, slot = c & 7;
                const float* src = Af + (size_t)(m0 + row) * DMODEL + k0 + slot * 8;
                float4 a = *(const float4*)src;
                float4 b = *(const float4*)(src + 4);
                short8 o;
                o[0] = f2bf(a.x); o[1] = f2bf(a.y); o[2] = f2bf(a.z); o[3] = f2bf(a.w);
                o[4] = f2bf(b.x); o[5] = f2bf(b.y); o[6] = f2bf(b.z); o[7] = f2bf(b.w);
                *(short8*)&As[(row * 8 + (slot ^ (row & 7))) * 8] = o;
            }
        } else {
            const short* Ab = (const short*)Avoid;
#pragma unroll
            for (int it = 0; it < 4; ++it) {       // A tile via global_load_lds
                int c = it * 256 + tid;
                int row = c >> 3, slot = c & 7;
                gl2lds16(Ab + (size_t)(m0 + row) * DMODEL + k0 + ((slot ^ (row & 7)) << 3), &As[c * 8]);
            }
        }
#pragma unroll
        for (int it = 0; it < 4; ++it) {           // B tile: 128 rows x 8 chunks
            int c = it * 256 + tid;
            int row = c >> 3, slot = c & 7;
            gl2lds16(Bt + (size_t)(n0 + row) * DMODEL + k0 + ((slot ^ (row & 7)) << 3), &Bs[c * 8]);
        }
        __syncthreads();
#pragma unroll
        for (int ks = 0; ks < 2; ++ks) {
            const int koff = ks * 4 + l4;
            short8 a[4], b[4];
#pragma unroll
            for (int fm = 0; fm < 4; ++fm) {
                int row = wr * 64 + fm * 16 + l15;
                a[fm] = *(const short8*)&As[(row * 8 + (koff ^ (row & 7))) * 8];
            }
#pragma unroll
            for (int fn = 0; fn < 4; ++fn) {
                int row = wc * 64 + fn * 16 + l15;
                b[fn] = *(const short8*)&Bs[(row * 8 + (koff ^ (row & 7))) * 8];
            }
#pragma unroll
            for (int fm = 0; fm < 4; ++fm)
#pragma unroll
                for (int fn = 0; fn < 4; ++fn)
                    acc[fm][fn] = __builtin_amdgcn_mfma_f32_16x16x32_bf16(
                        a[fm], b[fn], acc[fm][fn], 0, 0, 0);
        }
    }
#pragma unroll
    for (int fm = 0; fm < 4; ++fm)
#pragma unroll
        for (int fn = 0; fn < 4; ++fn) {
            if (OUTMODE == 2) {
                short4 o4;
                o4.x = f2bf(acc[fm][fn][0]);
                o4.y = f2bf(acc[fm][fn][1]);
                o4.z = f2bf(acc[fm][fn][2]);
                o4.w = f2bf(acc[fm][fn][3]);
                int m = m0 + wr * 64 + fm * 16 + l4 * 4;
                int bb = m >> 12, g = m & (L_Q - 1);
                int n = n0 + wc * 64 + fn * 16 + l15;
                int hh = n >> 6, dd = n & 63;
                *(short4*)&((short*)Cout)[(((size_t)bb * NHEAD + hh) * DHEAD + dd) * L_Q + g] = o4;
            } else {
#pragma unroll
                for (int i = 0; i < 4; ++i) {
                    size_t row = (size_t)(m0 + wr * 64 + fm * 16 + l4 * 4 + i);
                    int col = n0 + wc * 64 + fn * 16 + l15;
                    if (OUTMODE == 1) ((short*)Cout)[row * DMODEL + col] = f2bf(acc[fm][fn][i]);
                    else              ((float*)Cout)[row * DMODEL + col] = acc[fm][fn][i];
                }
            }
        }
}

// three projection GEMMs in one launch, f32 inputs cast in-staging:
// z=0 Q(bf16), z=1 K(bf16), z=2 V(transposed Vt[bh][d][g])
__global__ __launch_bounds__(256) void gemm_qkv(
    const float* __restrict__ q, const float* __restrict__ k, const float* __restrict__ v,
    const short* __restrict__ Wtq, const short* __restrict__ Wtk, const short* __restrict__ Wtv,
    short* __restrict__ Qp, short* __restrict__ Kp, short* __restrict__ Vt)
{
    __shared__ short As[128 * 64];
    __shared__ short Bs[128 * 64];
    const int z = blockIdx.z;
    const float* A  = (z == 0) ? q   : ((z == 1) ? k   : v);
    const short* Bt = (z == 0) ? Wtq : ((z == 1) ? Wtk : Wtv);
    if (z == 2) gemm128_body<2, true>(A, Bt, Vt, As, Bs);
    else        gemm128_body<1, true>(A, Bt, (z == 0) ? Qp : Kp, As, Bs);
}

__global__ __launch_bounds__(256) void gemm_fin(
    const short* __restrict__ Op, const short* __restrict__ Wto, float* __restrict__ out)
{
    __shared__ short As[128 * 64];
    __shared__ short Bs[128 * 64];
    gemm128_body<0, false>(Op, Wto, out, As, Bs);
}

// ---------------- attention pass A: band exp sums via MFMA ----------------
// grid (32, 8, 2), block 256 = 4 waves; wave w: queries [w*32, w*32+32)
__global__ __launch_bounds__(256) void attn_e(
    const short* __restrict__ Qp, const short* __restrict__ Kp,
    float* __restrict__ part)
{
    __shared__ short Ks[160 * 64];
    __shared__ short Qs[128 * 64];
    __shared__ float eb[128][36];
    __shared__ float red[8][32];
    const int tid = threadIdx.x;
    const int j0 = blockIdx.x * 128;
    const int h = blockIdx.y, b = blockIdx.z;
    const int bh = b * NHEAD + h;
    const int w = tid >> 6, lane = tid & 63;
    const int l15 = lane & 15, l4 = lane >> 4;

    {   // zero eb (invalid band slots must read 0)
        float4 z = make_float4(0.f, 0.f, 0.f, 0.f);
        float4* ebv = (float4*)&eb[0][0];
#pragma unroll
        for (int i = 0; i < 5; ++i) {
            int idx = i * 256 + tid;
            if (idx < 1152) ebv[idx] = z;
        }
    }
#pragma unroll
    for (int it = 0; it < 5; ++it) {   // K rows j0-31 .. j0+128
        int c = it * 256 + tid;
        int row = c >> 3, slot = c & 7;
        int g = j0 - 31 + row;
        g = (g < 0) ? 0 : ((g > L_Q - 1) ? L_Q - 1 : g);
        gl2lds16(Kp + ((size_t)b * L_Q + g) * DMODEL + h * DHEAD + ((slot ^ (row & 7)) << 3), &Ks[c * 8]);
    }
#pragma unroll
    for (int it = 0; it < 4; ++it) {   // Q rows j0 .. j0+127
        int c = it * 256 + tid;
        int row = c >> 3, slot = c & 7;
        gl2lds16(Qp + ((size_t)b * L_Q + j0 + row) * DMODEL + h * DHEAD + ((slot ^ (row & 7)) << 3), &Qs[c * 8]);
    }
    __syncthreads();

    // S[q 0..32)[rr 0..64): tiles tm(2) x tn(4), K=64
    f32x4 acc[2][4];
#pragma unroll
    for (int tm = 0; tm < 2; ++tm)
#pragma unroll
        for (int tn = 0; tn < 4; ++tn) acc[tm][tn] = (f32x4){0.f, 0.f, 0.f, 0.f};
#pragma unroll
    for (int kk = 0; kk < 2; ++kk) {
        const int koff = kk * 4 + l4;
        short8 af[2], bf[4];
#pragma unroll
        for (int tm = 0; tm < 2; ++tm) {
            int row = w * 32 + tm * 16 + l15;
            af[tm] = *(const short8*)&Qs[(row * 8 + (koff ^ (row & 7))) * 8];
        }
#pragma unroll
        for (int tn = 0; tn < 4; ++tn) {
            int row = w * 32 + tn * 16 + l15;
            bf[tn] = *(const short8*)&Ks[(row * 8 + (koff ^ (row & 7))) * 8];
        }
#pragma unroll
        for (int tm = 0; tm < 2; ++tm)
#pragma unroll
            for (int tn = 0; tn < 4; ++tn)
                acc[tm][tn] = __builtin_amdgcn_mfma_f32_16x16x32_bf16(
                    af[tm], bf[tn], acc[tm][tn], 0, 0, 0);
    }

    // band extract -> eb[q][r]
    const int gbase = j0 + w * 32 - 31;
#pragma unroll
    for (int tm = 0; tm < 2; ++tm)
#pragma unroll
        for (int tn = 0; tn < 4; ++tn)
#pragma unroll
            for (int i = 0; i < 4; ++i) {
                int q = tm * 16 + l4 * 4 + i;
                int rr = tn * 16 + l15;
                int r = rr - q;
                bool valid = (r >= 0) && (r < SPAN_) && (gbase + rr >= 0);
                if (valid) eb[w * 32 + q][r] = __expf(acc[tm][tn][i] * 0.125f);
            }
    __syncthreads();

    {   // reduce over q: thread t handles r = t&31, q-group t>>5
        int r = tid & 31, grp = tid >> 5;
        float s = 0.f;
#pragma unroll
        for (int qq = 0; qq < 16; ++qq) s += eb[grp * 16 + qq][r];
        red[grp][r] = s;
    }
    __syncthreads();
    if (tid < 32) {
        float s = 0.f;
#pragma unroll
        for (int g = 0; g < 8; ++g) s += red[g][tid];
        part[((size_t)bh * SPAN_ + tid) * 32 + blockIdx.x] = s;
    }
}

// ---------------- attention pass B: O = P @ V via MFMA (invE fused) ----------------
// grid (32, 8, 2), block 256 = 4 waves; wave w: queries [w*32, +32)
// K AND V windows based at j0-32 (chunk-aligned). Band: r = rrp - q - 1.
__global__ __launch_bounds__(256) void attn_o(
    const short* __restrict__ Qp, const short* __restrict__ Kp,
    const short* __restrict__ Vt, const float* __restrict__ part,
    short* __restrict__ Op)
{
    __shared__ short Ks[160 * 64];
    __shared__ short Qs[128 * 64];
    __shared__ short Vts[64 * 192];   // [d][g-window], 24 chunks/row, chunk-XOR swizzled
    const int tid = threadIdx.x;
    const int j0 = blockIdx.x * 128;
    const int h = blockIdx.y, b = blockIdx.z;
    const int bh = b * NHEAD + h;
    const int w = tid >> 6, lane = tid & 63;
    const int l15 = lane & 15, l4 = lane >> 4;

#pragma unroll
    for (int it = 0; it < 5; ++it) {   // K rows, window [j0-32, j0+128)
        int c = it * 256 + tid;
        int row = c >> 3, slot = c & 7;
        int g = j0 - 32 + row;
        g = (g < 0) ? 0 : ((g > L_Q - 1) ? L_Q - 1 : g);
        gl2lds16(Kp + ((size_t)b * L_Q + g) * DMODEL + h * DHEAD + ((slot ^ (row & 7)) << 3), &Ks[c * 8]);
    }
#pragma unroll
    for (int it = 0; it < 4; ++it) {   // Q rows
        int c = it * 256 + tid;
        int row = c >> 3, slot = c & 7;
        gl2lds16(Qp + ((size_t)b * L_Q + j0 + row) * DMODEL + h * DHEAD + ((slot ^ (row & 7)) << 3), &Qs[c * 8]);
    }
#pragma unroll
    for (int it = 0; it < 6; ++it) {   // V^T: 64 d-rows x 24 chunks, window [j0-32, j0+160)
        int c = it * 256 + tid;
        int d = c / 24, cs = c - d * 24;
        int gg = j0 - 32 + ((cs ^ (d & 7)) << 3);
        gg = (gg < 0) ? 0 : ((gg > L_Q - 8) ? L_Q - 8 : gg);   // clamped chunks fully masked
        gl2lds16(Vt + ((size_t)bh * DHEAD + d) * L_Q + gg, &Vts[c * 8]);
    }

    // fused invE: lane's r = lane&31; part row [r][0..32) summed in fixed order
    float iv;
    {
        const float4* pp = (const float4*)(part + ((size_t)bh * SPAN_ + (lane & 31)) * 32);
        float s = 0.f;
#pragma unroll
        for (int i = 0; i < 8; ++i) {
            float4 t = pp[i];
            s += t.x + t.y + t.z + t.w;
        }
        iv = 1.0f / s;
    }
    __syncthreads();

    // S^T[rrp 0..64)[q 0..32): tiles tk(4) x tq(2)
    f32x4 sa[4][2];
#pragma unroll
    for (int tk = 0; tk < 4; ++tk)
#pragma unroll
        for (int tq = 0; tq < 2; ++tq) sa[tk][tq] = (f32x4){0.f, 0.f, 0.f, 0.f};
#pragma unroll
    for (int kk = 0; kk < 2; ++kk) {
        const int koff = kk * 4 + l4;
        short8 af[4], qf[2];
#pragma unroll
        for (int tk = 0; tk < 4; ++tk) {
            int row = w * 32 + tk * 16 + l15;
            af[tk] = *(const short8*)&Ks[(row * 8 + (koff ^ (row & 7))) * 8];
        }
#pragma unroll
        for (int tq = 0; tq < 2; ++tq) {
            int row = w * 32 + tq * 16 + l15;
            qf[tq] = *(const short8*)&Qs[(row * 8 + (koff ^ (row & 7))) * 8];
        }
#pragma unroll
        for (int tk = 0; tk < 4; ++tk)
#pragma unroll
            for (int tq = 0; tq < 2; ++tq)
                sa[tk][tq] = __builtin_amdgcn_mfma_f32_16x16x32_bf16(
                    af[tk], qf[tq], sa[tk][tq], 0, 0, 0);
    }

    // w = exp(s/8) * invE[r], masked; r = rrp - q - 1 (window base j0-32)
    const int gbase = j0 + w * 32 - 32;
#pragma unroll
    for (int tk = 0; tk < 4; ++tk)
#pragma unroll
        for (int tq = 0; tq < 2; ++tq)
#pragma unroll
            for (int i = 0; i < 4; ++i) {
                int rrp = tk * 16 + l4 * 4 + i;
                int q = tq * 16 + l15;
                int r = rrp - q - 1;
                bool valid = (r >= 0) && (r < SPAN_) && (gbase + rrp >= 0);
                float e = __expf(sa[tk][tq][i] * 0.125f) * __shfl(iv, r & 31);
                sa[tk][tq][i] = valid ? e : 0.f;
            }

    // pack to bf16 pairs: pk[tk][tq][2]
    unsigned pk[4][2][2];
#pragma unroll
    for (int tk = 0; tk < 4; ++tk)
#pragma unroll
        for (int tq = 0; tq < 2; ++tq) {
            pk[tk][tq][0] = packbf(sa[tk][tq][0], sa[tk][tq][1]);
            pk[tk][tq][1] = packbf(sa[tk][tq][2], sa[tk][tq][3]);
        }

    // P -> PV A-fragment: dest lane (l4,l15), word j' of pa[tm] =
    //   pk[kk*2 + (l4>>1)][tm][j'&1] from lane ((l4&1)*2 + (j'>>1))*16 + l15.
    // Shuffle BOTH register candidates, select by hi on destination.
    const int hi = l4 >> 1;
    const int lsA = ((l4 & 1) << 5) + l15;

    // PV: O[q 32][d 64] tiles tm(2) x dn(4), K = 64 (rrp)
    f32x4 oa[2][4];
#pragma unroll
    for (int tm = 0; tm < 2; ++tm)
#pragma unroll
        for (int dn = 0; dn < 4; ++dn) oa[tm][dn] = (f32x4){0.f, 0.f, 0.f, 0.f};
#pragma unroll
    for (int kk = 0; kk < 2; ++kk) {
        short8 pa[2];
#pragma unroll
        for (int tm = 0; tm < 2; ++tm) {
            unsigned lo00 = (unsigned)__shfl((int)pk[kk * 2 + 0][tm][0], lsA);
            unsigned hi00 = (unsigned)__shfl((int)pk[kk * 2 + 1][tm][0], lsA);
            unsigned lo01 = (unsigned)__shfl((int)pk[kk * 2 + 0][tm][1], lsA);
            unsigned hi01 = (unsigned)__shfl((int)pk[kk * 2 + 1][tm][1], lsA);
            unsigned lo10 = (unsigned)__shfl((int)pk[kk * 2 + 0][tm][0], lsA + 16);
            unsigned hi10 = (unsigned)__shfl((int)pk[kk * 2 + 1][tm][0], lsA + 16);
            unsigned lo11 = (unsigned)__shfl((int)pk[kk * 2 + 0][tm][1], lsA + 16);
            unsigned hi11 = (unsigned)__shfl((int)pk[kk * 2 + 1][tm][1], lsA + 16);
            uint4 wds;
            wds.x = hi ? hi00 : lo00;
            wds.y = hi ? hi01 : lo01;
            wds.z = hi ? hi10 : lo10;
            wds.w = hi ? hi11 : lo11;
            pa[tm] = *reinterpret_cast<short8*>(&wds);
        }
#pragma unroll
        for (int dn = 0; dn < 4; ++dn) {
            int row = dn * 16 + l15;
            int cs = w * 4 + kk * 4 + l4;
            short8 vb = *(const short8*)&Vts[row * 192 + ((cs ^ (row & 7)) << 3)];
#pragma unroll
            for (int tm = 0; tm < 2; ++tm)
                oa[tm][dn] = __builtin_amdgcn_mfma_f32_16x16x32_bf16(
                    pa[tm], vb, oa[tm][dn], 0, 0, 0);
        }
    }

    // store O (bf16 row-major [token][512])
#pragma unroll
    for (int tm = 0; tm < 2; ++tm)
#pragma unroll
        for (int dn = 0; dn < 4; ++dn)
#pragma unroll
            for (int i = 0; i < 4; ++i) {
                int q = w * 32 + tm * 16 + l4 * 4 + i;
                Op[((size_t)b * L_Q + j0 + q) * DMODEL + h * DHEAD + dn * 16 + l15] =
                    f2bf(oa[tm][dn][i]);
            }
}

extern "C" void kernel_launch(void* const* d_in, const int* in_sizes, int n_in,
                              void* d_out, int out_size, void* d_ws, size_t ws_size,
                              hipStream_t stream) {
    (void)in_sizes; (void)n_in; (void)out_size; (void)ws_size;
    const float* q  = (const float*)d_in[0];
    const float* k  = (const float*)d_in[1];
    const float* v  = (const float*)d_in[2];
    const float* Wq = (const float*)d_in[3];
    const float* Wk = (const float*)d_in[4];
    const float* Wv = (const float*)d_in[5];
    const float* Wo = (const float*)d_in[6];
    float* out = (float*)d_out;

    char* ws = (char*)d_ws;
    const size_t MiB = 1ull << 20;
    short* Wtq = (short*)(ws);
    short* Wtk = (short*)(ws + 512 * 1024);
    short* Wtv = (short*)(ws + 1 * MiB);
    short* Wto = (short*)(ws + 1 * MiB + 512 * 1024);
    short* Qp  = (short*)(ws + 2 * MiB);
    short* Kp  = (short*)(ws + 10 * MiB);
    short* Vtp = (short*)(ws + 18 * MiB);
    short* Op  = (short*)(ws + 26 * MiB);
    float* part = (float*)(ws + 34 * MiB);

    castT4_bf16<<<dim3(16, 16, 4), dim3(32, 8), 0, stream>>>(
        Wq, Wk, Wv, Wo, Wtq, Wtk, Wtv, Wto);

    gemm_qkv<<<dim3(4, 64, 3), 256, 0, stream>>>(q, k, v, Wtq, Wtk, Wtv, Qp, Kp, Vtp);

    dim3 ga(L_Q / 128, NHEAD, NB);  // (32, 8, 2)
    attn_e<<<ga, 256, 0, stream>>>(Qp, Kp, part);
    attn_o<<<ga, 256, 0, stream>>>(Qp, Kp, Vtp, part, Op);

    gemm_fin<<<dim3(4, 64), 256, 0, stream>>>(Op, Wto, out);
}

// Round 7
// 63.211 us; speedup vs baseline: 1.2231x; 1.2231x over previous
//
#include <hip/hip_runtime.h>
#include <hip/hip_bf16.h>

#define L_Q 4096
#define NB 2
#define DMODEL 512
#define NHEAD 8
#define DHEAD 64
#define SPAN_ 32

using short8 = __attribute__((ext_vector_type(8))) short;
using f32x4  = __attribute__((ext_vector_type(4))) float;

typedef __attribute__((address_space(1))) const void GV;
typedef __attribute__((address_space(3))) void LV;

__device__ __forceinline__ void gl2lds16(const void* g, void* l) {
    __builtin_amdgcn_global_load_lds((GV*)g, (LV*)l, 16, 0, 0);
}

__device__ __forceinline__ float bf2f(short u) {
    return __uint_as_float(((unsigned)(unsigned short)u) << 16);
}
__device__ __forceinline__ short f2bf(float f) {
    __hip_bfloat16 h = __float2bfloat16(f);
    return *reinterpret_cast<short*>(&h);
}
__device__ __forceinline__ unsigned packbf(float lo, float hi) {
    return (unsigned)(unsigned short)f2bf(lo) | ((unsigned)(unsigned short)f2bf(hi) << 16);
}

// ---------------- weight transpose+cast x4: Wt[n][k] = bf16(W[k][n]) ----------------
__global__ __launch_bounds__(256) void castT4_bf16(
    const float* __restrict__ Wq, const float* __restrict__ Wk,
    const float* __restrict__ Wv, const float* __restrict__ Wo,
    short* __restrict__ Wtq, short* __restrict__ Wtk,
    short* __restrict__ Wtv, short* __restrict__ Wto)
{
    const int z = blockIdx.z;
    const float* W = (z == 0) ? Wq : ((z == 1) ? Wk : ((z == 2) ? Wv : Wo));
    short* Wt = (z == 0) ? Wtq : ((z == 1) ? Wtk : ((z == 2) ? Wtv : Wto));
    __shared__ float t[32][33];
    const int tx = threadIdx.x, ty = threadIdx.y;
    const int bx = blockIdx.x, by = blockIdx.y;
#pragma unroll
    for (int i = 0; i < 4; ++i)
        t[ty + i * 8][tx] = W[(size_t)(by * 32 + ty + i * 8) * DMODEL + bx * 32 + tx];
    __syncthreads();
#pragma unroll
    for (int i = 0; i < 4; ++i)
        Wt[(size_t)(bx * 32 + ty + i * 8) * DMODEL + by * 32 + tx] = f2bf(t[tx][ty + i * 8]);
}

// XCD-grouping swizzle for grid (4, 64, z): all 4 n-tiles of an m-tile land on
// one XCD (its private L2 then serves the shared A-panel). hw = bx + 4*by is
// the hardware dispatch index; XCDs are assumed round-robin in hw order.
__device__ __forceinline__ void xcd_swizzle(int& m0, int& n0) {
    int hw = blockIdx.x + (blockIdx.y << 2);   // [0,256)
    int xcd = hw & 7, slot = hw >> 3;          // 8 XCDs x 32 slots
    int mt = xcd * 8 + (slot >> 2);            // m-tile [0,64)
    int nt = slot & 3;                         // n-tile [0,4)
    m0 = mt * 128;
    n0 = nt * 128;
}

// ---------------- 128x128 MFMA GEMM core (BK=64, 4 waves, wave = 64x64) ----------------
// OUTMODE 0: f32 row-major. 1: bf16 row-major. 2: bf16 Vt[bh][d][g].
// ACAST: A is f32, cast to bf16 during reg-staging (prefetched across compute).
template<int OUTMODE, bool ACAST>
__device__ __forceinline__ void gemm128_body(
    const void* __restrict__ Avoid, const short* __restrict__ Bt, void* __restrict__ Cout,
    short* As, short* Bs, int m0, int n0)
{
    const int tid = threadIdx.x;
    const int w = tid >> 6, lane = tid & 63;
    const int wr = w & 1, wc = w >> 1;
    const int l15 = lane & 15, l4 = lane >> 4;
    const float* Af = (const float*)Avoid;

    f32x4 acc[4][4];
#pragma unroll
    for (int fm = 0; fm < 4; ++fm)
#pragma unroll
        for (int fn = 0; fn < 4; ++fn) acc[fm][fn] = (f32x4){0.f, 0.f, 0.f, 0.f};

    float4 pf[8];
    if (ACAST) {
#pragma unroll
        for (int it = 0; it < 4; ++it) {       // prologue: A chunk loads for k0=0
            int c = it * 256 + tid;
            int row = c >> 3, slot = c & 7;
            const float* src = Af + (size_t)(m0 + row) * DMODEL + slot * 8;
            pf[it * 2 + 0] = *(const float4*)src;
            pf[it * 2 + 1] = *(const float4*)(src + 4);
        }
    }

    for (int k0 = 0; k0 < DMODEL; k0 += 64) {
        __syncthreads();
        if (ACAST) {
#pragma unroll
            for (int it = 0; it < 4; ++it) {   // cvt + swizzled ds_write
                int c = it * 256 + tid;
                int row = c >> 3, slot = c & 7;
                float4 a = pf[it * 2 + 0], b = pf[it * 2 + 1];
                short8 o;
                o[0] = f2bf(a.x); o[1] = f2bf(a.y); o[2] = f2bf(a.z); o[3] = f2bf(a.w);
                o[4] = f2bf(b.x); o[5] = f2bf(b.y); o[6] = f2bf(b.z); o[7] = f2bf(b.w);
                *(short8*)&As[(row * 8 + (slot ^ (row & 7))) * 8] = o;
            }
        } else {
            const short* Ab = (const short*)Avoid;
#pragma unroll
            for (int it = 0; it < 4; ++it) {
                int c = it * 256 + tid;
                int row = c >> 3, slot = c & 7;
                gl2lds16(Ab + (size_t)(m0 + row) * DMODEL + k0 + ((slot ^ (row & 7)) << 3), &As[c * 8]);
            }
        }
#pragma unroll
        for (int it = 0; it < 4; ++it) {       // B tile: 128 rows x 8 chunks
            int c = it * 256 + tid;
            int row = c >> 3, slot = c & 7;
            gl2lds16(Bt + (size_t)(n0 + row) * DMODEL + k0 + ((slot ^ (row & 7)) << 3), &Bs[c * 8]);
        }
        __syncthreads();
        if (ACAST && k0 + 64 < DMODEL) {       // prefetch next A under the MFMA phase
#pragma unroll
            for (int it = 0; it < 4; ++it) {
                int c = it * 256 + tid;
                int row = c >> 3, slot = c & 7;
                const float* src = Af + (size_t)(m0 + row) * DMODEL + (k0 + 64) + slot * 8;
                pf[it * 2 + 0] = *(const float4*)src;
                pf[it * 2 + 1] = *(const float4*)(src + 4);
            }
        }
#pragma unroll
        for (int ks = 0; ks < 2; ++ks) {
            const int koff = ks * 4 + l4;
            short8 a[4], b[4];
#pragma unroll
            for (int fm = 0; fm < 4; ++fm) {
                int row = wr * 64 + fm * 16 + l15;
                a[fm] = *(const short8*)&As[(row * 8 + (koff ^ (row & 7))) * 8];
            }
#pragma unroll
            for (int fn = 0; fn < 4; ++fn) {
                int row = wc * 64 + fn * 16 + l15;
                b[fn] = *(const short8*)&Bs[(row * 8 + (koff ^ (row & 7))) * 8];
            }
#pragma unroll
            for (int fm = 0; fm < 4; ++fm)
#pragma unroll
                for (int fn = 0; fn < 4; ++fn)
                    acc[fm][fn] = __builtin_amdgcn_mfma_f32_16x16x32_bf16(
                        a[fm], b[fn], acc[fm][fn], 0, 0, 0);
        }
    }
#pragma unroll
    for (int fm = 0; fm < 4; ++fm)
#pragma unroll
        for (int fn = 0; fn < 4; ++fn) {
            if (OUTMODE == 2) {
                short4 o4;
                o4.x = f2bf(acc[fm][fn][0]);
                o4.y = f2bf(acc[fm][fn][1]);
                o4.z = f2bf(acc[fm][fn][2]);
                o4.w = f2bf(acc[fm][fn][3]);
                int m = m0 + wr * 64 + fm * 16 + l4 * 4;
                int bb = m >> 12, g = m & (L_Q - 1);
                int n = n0 + wc * 64 + fn * 16 + l15;
                int hh = n >> 6, dd = n & 63;
                *(short4*)&((short*)Cout)[(((size_t)bb * NHEAD + hh) * DHEAD + dd) * L_Q + g] = o4;
            } else {
#pragma unroll
                for (int i = 0; i < 4; ++i) {
                    size_t row = (size_t)(m0 + wr * 64 + fm * 16 + l4 * 4 + i);
                    int col = n0 + wc * 64 + fn * 16 + l15;
                    if (OUTMODE == 1) ((short*)Cout)[row * DMODEL + col] = f2bf(acc[fm][fn][i]);
                    else              ((float*)Cout)[row * DMODEL + col] = acc[fm][fn][i];
                }
            }
        }
}

// three projection GEMMs in one launch, f32 inputs cast in-staging:
// z=0 Q(bf16), z=1 K(bf16), z=2 V(transposed Vt[bh][d][g])
__global__ __launch_bounds__(256) void gemm_qkv(
    const float* __restrict__ q, const float* __restrict__ k, const float* __restrict__ v,
    const short* __restrict__ Wtq, const short* __restrict__ Wtk, const short* __restrict__ Wtv,
    short* __restrict__ Qp, short* __restrict__ Kp, short* __restrict__ Vt)
{
    __shared__ short As[128 * 64];
    __shared__ short Bs[128 * 64];
    int m0, n0;
    xcd_swizzle(m0, n0);
    const int z = blockIdx.z;
    const float* A  = (z == 0) ? q   : ((z == 1) ? k   : v);
    const short* Bt = (z == 0) ? Wtq : ((z == 1) ? Wtk : Wtv);
    if (z == 2) gemm128_body<2, true>(A, Bt, Vt, As, Bs, m0, n0);
    else        gemm128_body<1, true>(A, Bt, (z == 0) ? Qp : Kp, As, Bs, m0, n0);
}

__global__ __launch_bounds__(256) void gemm_fin(
    const short* __restrict__ Op, const short* __restrict__ Wto, float* __restrict__ out)
{
    __shared__ short As[128 * 64];
    __shared__ short Bs[128 * 64];
    int m0, n0;
    xcd_swizzle(m0, n0);
    gemm128_body<0, false>(Op, Wto, out, As, Bs, m0, n0);
}

// ---------------- attention pass A: band exp sums via MFMA ----------------
// grid (32, 8, 2), block 256 = 4 waves; wave w: queries [w*32, w*32+32)
__global__ __launch_bounds__(256) void attn_e(
    const short* __restrict__ Qp, const short* __restrict__ Kp,
    float* __restrict__ part)
{
    __shared__ short Ks[160 * 64];
    __shared__ short Qs[128 * 64];
    __shared__ float eb[128][36];
    __shared__ float red[8][32];
    const int tid = threadIdx.x;
    const int j0 = blockIdx.x * 128;
    const int h = blockIdx.y, b = blockIdx.z;
    const int bh = b * NHEAD + h;
    const int w = tid >> 6, lane = tid & 63;
    const int l15 = lane & 15, l4 = lane >> 4;

    {   // zero eb (invalid band slots must read 0)
        float4 z = make_float4(0.f, 0.f, 0.f, 0.f);
        float4* ebv = (float4*)&eb[0][0];
#pragma unroll
        for (int i = 0; i < 5; ++i) {
            int idx = i * 256 + tid;
            if (idx < 1152) ebv[idx] = z;
        }
    }
#pragma unroll
    for (int it = 0; it < 5; ++it) {   // K rows j0-31 .. j0+128
        int c = it * 256 + tid;
        int row = c >> 3, slot = c & 7;
        int g = j0 - 31 + row;
        g = (g < 0) ? 0 : ((g > L_Q - 1) ? L_Q - 1 : g);
        gl2lds16(Kp + ((size_t)b * L_Q + g) * DMODEL + h * DHEAD + ((slot ^ (row & 7)) << 3), &Ks[c * 8]);
    }
#pragma unroll
    for (int it = 0; it < 4; ++it) {   // Q rows j0 .. j0+127
        int c = it * 256 + tid;
        int row = c >> 3, slot = c & 7;
        gl2lds16(Qp + ((size_t)b * L_Q + j0 + row) * DMODEL + h * DHEAD + ((slot ^ (row & 7)) << 3), &Qs[c * 8]);
    }
    __syncthreads();

    // S[q 0..32)[rr 0..64): tiles tm(2) x tn(4), K=64
    f32x4 acc[2][4];
#pragma unroll
    for (int tm = 0; tm < 2; ++tm)
#pragma unroll
        for (int tn = 0; tn < 4; ++tn) acc[tm][tn] = (f32x4){0.f, 0.f, 0.f, 0.f};
#pragma unroll
    for (int kk = 0; kk < 2; ++kk) {
        const int koff = kk * 4 + l4;
        short8 af[2], bf[4];
#pragma unroll
        for (int tm = 0; tm < 2; ++tm) {
            int row = w * 32 + tm * 16 + l15;
            af[tm] = *(const short8*)&Qs[(row * 8 + (koff ^ (row & 7))) * 8];
        }
#pragma unroll
        for (int tn = 0; tn < 4; ++tn) {
            int row = w * 32 + tn * 16 + l15;
            bf[tn] = *(const short8*)&Ks[(row * 8 + (koff ^ (row & 7))) * 8];
        }
#pragma unroll
        for (int tm = 0; tm < 2; ++tm)
#pragma unroll
            for (int tn = 0; tn < 4; ++tn)
                acc[tm][tn] = __builtin_amdgcn_mfma_f32_16x16x32_bf16(
                    af[tm], bf[tn], acc[tm][tn], 0, 0, 0);
    }

    // band extract -> eb[q][r]
    const int gbase = j0 + w * 32 - 31;
#pragma unroll
    for (int tm = 0; tm < 2; ++tm)
#pragma unroll
        for (int tn = 0; tn < 4; ++tn)
#pragma unroll
            for (int i = 0; i < 4; ++i) {
                int q = tm * 16 + l4 * 4 + i;
                int rr = tn * 16 + l15;
                int r = rr - q;
                bool valid = (r >= 0) && (r < SPAN_) && (gbase + rr >= 0);
                if (valid) eb[w * 32 + q][r] = __expf(acc[tm][tn][i] * 0.125f);
            }
    __syncthreads();

    {   // reduce over q: thread t handles r = t&31, q-group t>>5
        int r = tid & 31, grp = tid >> 5;
        float s = 0.f;
#pragma unroll
        for (int qq = 0; qq < 16; ++qq) s += eb[grp * 16 + qq][r];
        red[grp][r] = s;
    }
    __syncthreads();
    if (tid < 32) {
        float s = 0.f;
#pragma unroll
        for (int g = 0; g < 8; ++g) s += red[g][tid];
        part[((size_t)bh * SPAN_ + tid) * 32 + blockIdx.x] = s;
    }
}

// ---------------- attention pass B: O = P @ V via MFMA (invE fused) ----------------
// grid (32, 8, 2), block 256 = 4 waves; wave w: queries [w*32, +32)
// K AND V windows based at j0-32 (chunk-aligned). Band: r = rrp - q - 1.
__global__ __launch_bounds__(256) void attn_o(
    const short* __restrict__ Qp, const short* __restrict__ Kp,
    const short* __restrict__ Vt, const float* __restrict__ part,
    short* __restrict__ Op)
{
    __shared__ short Ks[160 * 64];
    __shared__ short Qs[128 * 64];
    __shared__ short Vts[64 * 192];   // [d][g-window], 24 chunks/row, chunk-XOR swizzled
    const int tid = threadIdx.x;
    const int j0 = blockIdx.x * 128;
    const int h = blockIdx.y, b = blockIdx.z;
    const int bh = b * NHEAD + h;
    const int w = tid >> 6, lane = tid & 63;
    const int l15 = lane & 15, l4 = lane >> 4;

#pragma unroll
    for (int it = 0; it < 5; ++it) {   // K rows, window [j0-32, j0+128)
        int c = it * 256 + tid;
        int row = c >> 3, slot = c & 7;
        int g = j0 - 32 + row;
        g = (g < 0) ? 0 : ((g > L_Q - 1) ? L_Q - 1 : g);
        gl2lds16(Kp + ((size_t)b * L_Q + g) * DMODEL + h * DHEAD + ((slot ^ (row & 7)) << 3), &Ks[c * 8]);
    }
#pragma unroll
    for (int it = 0; it < 4; ++it) {   // Q rows
        int c = it * 256 + tid;
        int row = c >> 3, slot = c & 7;
        gl2lds16(Qp + ((size_t)b * L_Q + j0 + row) * DMODEL + h * DHEAD + ((slot ^ (row & 7)) << 3), &Qs[c * 8]);
    }
#pragma unroll
    for (int it = 0; it < 6; ++it) {   // V^T: 64 d-rows x 24 chunks, window [j0-32, j0+160)
        int c = it * 256 + tid;
        int d = c / 24, cs = c - d * 24;
        int gg = j0 - 32 + ((cs ^ (d & 7)) << 3);
        gg = (gg < 0) ? 0 : ((gg > L_Q - 8) ? L_Q - 8 : gg);   // clamped chunks fully masked
        gl2lds16(Vt + ((size_t)bh * DHEAD + d) * L_Q + gg, &Vts[c * 8]);
    }

    // fused invE: lane's r = lane&31; part row [r][0..32) summed in fixed order
    float iv;
    {
        const float4* pp = (const float4*)(part + ((size_t)bh * SPAN_ + (lane & 31)) * 32);
        float s = 0.f;
#pragma unroll
        for (int i = 0; i < 8; ++i) {
            float4 t = pp[i];
            s += t.x + t.y + t.z + t.w;
        }
        iv = 1.0f / s;
    }
    __syncthreads();

    // S^T[rrp 0..64)[q 0..32): tiles tk(4) x tq(2)
    f32x4 sa[4][2];
#pragma unroll
    for (int tk = 0; tk < 4; ++tk)
#pragma unroll
        for (int tq = 0; tq < 2; ++tq) sa[tk][tq] = (f32x4){0.f, 0.f, 0.f, 0.f};
#pragma unroll
    for (int kk = 0; kk < 2; ++kk) {
        const int koff = kk * 4 + l4;
        short8 af[4], qf[2];
#pragma unroll
        for (int tk = 0; tk < 4; ++tk) {
            int row = w * 32 + tk * 16 + l15;
            af[tk] = *(const short8*)&Ks[(row * 8 + (koff ^ (row & 7))) * 8];
        }
#pragma unroll
        for (int tq = 0; tq < 2; ++tq) {
            int row = w * 32 + tq * 16 + l15;
            qf[tq] = *(const short8*)&Qs[(row * 8 + (koff ^ (row & 7))) * 8];
        }
#pragma unroll
        for (int tk = 0; tk < 4; ++tk)
#pragma unroll
            for (int tq = 0; tq < 2; ++tq)
                sa[tk][tq] = __builtin_amdgcn_mfma_f32_16x16x32_bf16(
                    af[tk], qf[tq], sa[tk][tq], 0, 0, 0);
    }

    // w = exp(s/8) * invE[r], masked; r = rrp - q - 1 (window base j0-32)
    const int gbase = j0 + w * 32 - 32;
#pragma unroll
    for (int tk = 0; tk < 4; ++tk)
#pragma unroll
        for (int tq = 0; tq < 2; ++tq)
#pragma unroll
            for (int i = 0; i < 4; ++i) {
                int rrp = tk * 16 + l4 * 4 + i;
                int q = tq * 16 + l15;
                int r = rrp - q - 1;
                bool valid = (r >= 0) && (r < SPAN_) && (gbase + rrp >= 0);
                float e = __expf(sa[tk][tq][i] * 0.125f) * __shfl(iv, r & 31);
                sa[tk][tq][i] = valid ? e : 0.f;
            }

    // pack to bf16 pairs: pk[tk][tq][2]
    unsigned pk[4][2][2];
#pragma unroll
    for (int tk = 0; tk < 4; ++tk)
#pragma unroll
        for (int tq = 0; tq < 2; ++tq) {
            pk[tk][tq][0] = packbf(sa[tk][tq][0], sa[tk][tq][1]);
            pk[tk][tq][1] = packbf(sa[tk][tq][2], sa[tk][tq][3]);
        }

    // P -> PV A-fragment: dest lane (l4,l15), word j' of pa[tm] =
    //   pk[kk*2 + (l4>>1)][tm][j'&1] from lane ((l4&1)*2 + (j'>>1))*16 + l15.
    // Shuffle BOTH register candidates, select by hi on destination.
    const int hi = l4 >> 1;
    const int lsA = ((l4 & 1) << 5) + l15;

    // PV: O[q 32][d 64] tiles tm(2) x dn(4), K = 64 (rrp)
    f32x4 oa[2][4];
#pragma unroll
    for (int tm = 0; tm < 2; ++tm)
#pragma unroll
        for (int dn = 0; dn < 4; ++dn) oa[tm][dn] = (f32x4){0.f, 0.f, 0.f, 0.f};
#pragma unroll
    for (int kk = 0; kk < 2; ++kk) {
        short8 pa[2];
#pragma unroll
        for (int tm = 0; tm < 2; ++tm) {
            unsigned lo00 = (unsigned)__shfl((int)pk[kk * 2 + 0][tm][0], lsA);
            unsigned hi00 = (unsigned)__shfl((int)pk[kk * 2 + 1][tm][0], lsA);
            unsigned lo01 = (unsigned)__shfl((int)pk[kk * 2 + 0][tm][1], lsA);
            unsigned hi01 = (unsigned)__shfl((int)pk[kk * 2 + 1][tm][1], lsA);
            unsigned lo10 = (unsigned)__shfl((int)pk[kk * 2 + 0][tm][0], lsA + 16);
            unsigned hi10 = (unsigned)__shfl((int)pk[kk * 2 + 1][tm][0], lsA + 16);
            unsigned lo11 = (unsigned)__shfl((int)pk[kk * 2 + 0][tm][1], lsA + 16);
            unsigned hi11 = (unsigned)__shfl((int)pk[kk * 2 + 1][tm][1], lsA + 16);
            uint4 wds;
            wds.x = hi ? hi00 : lo00;
            wds.y = hi ? hi01 : lo01;
            wds.z = hi ? hi10 : lo10;
            wds.w = hi ? hi11 : lo11;
            pa[tm] = *reinterpret_cast<short8*>(&wds);
        }
#pragma unroll
        for (int dn = 0; dn < 4; ++dn) {
            int row = dn * 16 + l15;
            int cs = w * 4 + kk * 4 + l4;
            short8 vb = *(const short8*)&Vts[row * 192 + ((cs ^ (row & 7)) << 3)];
#pragma unroll
            for (int tm = 0; tm < 2; ++tm)
                oa[tm][dn] = __builtin_amdgcn_mfma_f32_16x16x32_bf16(
                    pa[tm], vb, oa[tm][dn], 0, 0, 0);
        }
    }

    // store O (bf16 row-major [token][512])
#pragma unroll
    for (int tm = 0; tm < 2; ++tm)
#pragma unroll
        for (int dn = 0; dn < 4; ++dn)
#pragma unroll
            for (int i = 0; i < 4; ++i) {
                int q = w * 32 + tm * 16 + l4 * 4 + i;
                Op[((size_t)b * L_Q + j0 + q) * DMODEL + h * DHEAD + dn * 16 + l15] =
                    f2bf(oa[tm][dn][i]);
            }
}

extern "C" void kernel_launch(void* const* d_in, const int* in_sizes, int n_in,
                              void* d_out, int out_size, void* d_ws, size_t ws_size,
                              hipStream_t stream) {
    (void)in_sizes; (void)n_in; (void)out_size; (void)ws_size;
    const float* q  = (const float*)d_in[0];
    const float* k  = (const float*)d_in[1];
    const float* v  = (const float*)d_in[2];
    const float* Wq = (const float*)d_in[3];
    const float* Wk = (const float*)d_in[4];
    const float* Wv = (const float*)d_in[5];
    const float* Wo = (const float*)d_in[6];
    float* out = (float*)d_out;

    char* ws = (char*)d_ws;
    const size_t MiB = 1ull << 20;
    short* Wtq = (short*)(ws);
    short* Wtk = (short*)(ws + 512 * 1024);
    short* Wtv = (short*)(ws + 1 * MiB);
    short* Wto = (short*)(ws + 1 * MiB + 512 * 1024);
    short* Qp  = (short*)(ws + 2 * MiB);
    short* Kp  = (short*)(ws + 10 * MiB);
    short* Vtp = (short*)(ws + 18 * MiB);
    short* Op  = (short*)(ws + 26 * MiB);
    float* part = (float*)(ws + 34 * MiB);

    castT4_bf16<<<dim3(16, 16, 4), dim3(32, 8), 0, stream>>>(
        Wq, Wk, Wv, Wo, Wtq, Wtk, Wtv, Wto);

    gemm_qkv<<<dim3(4, 64, 3), 256, 0, stream>>>(q, k, v, Wtq, Wtk, Wtv, Qp, Kp, Vtp);

    dim3 ga(L_Q / 128, NHEAD, NB);  // (32, 8, 2)
    attn_e<<<ga, 256, 0, stream>>>(Qp, Kp, part);
    attn_o<<<ga, 256, 0, stream>>>(Qp, Kp, Vtp, part, Op);

    gemm_fin<<<dim3(4, 64), 256, 0, stream>>>(Op, Wto, out);
}